// Round 1
// baseline (513.707 us; speedup 1.0000x reference)
//
#include <hip/hip_runtime.h>
#include <stdint.h>

// DomainAttentionLayer: out = softmax((x Wq^T + bq)(dx Wk^T + bk)^T / sqrt(D)) (dx Wv^T + bv)
// N = M = 8192, D = 512, fp32 in/out; internal compute bf16 MFMA (threshold is bf16-scale).
//
// Pipeline:
//   1) qkv_proj  : bf16 GEMMs (convert-on-stage), bias fused; V stored transposed VT[D][M]
//   2) flash_attn: fused online-softmax attention, split-m x2 partials
//   3) combine   : exact log-sum-exp merge of partials -> fp32 out

#define DEV __device__ __forceinline__

typedef short short8 __attribute__((ext_vector_type(8)));     // 8 bf16 (4 VGPRs) MFMA frag
typedef float floatx4 __attribute__((ext_vector_type(4)));    // MFMA accum
typedef unsigned int uintx4 __attribute__((ext_vector_type(4)));
typedef unsigned short ushortx4 __attribute__((ext_vector_type(4)));

constexpr int NN = 8192;
constexpr int MM = 8192;
constexpr int DD = 512;
constexpr int SPLITS = 2;                       // split-m factor for flash
constexpr float SCALE2 = 0.0637587160f;         // log2(e) / sqrt(512)

#define NEG_INF (-__builtin_inff())

#if defined(__has_builtin)
#if __has_builtin(__builtin_amdgcn_exp2f)
#define EXP2F(x) __builtin_amdgcn_exp2f(x)
#else
#define EXP2F(x) exp2f(x)
#endif
#else
#define EXP2F(x) exp2f(x)
#endif

DEV unsigned short f2bf(float f) {              // RNE fp32 -> bf16 bits
  unsigned u = __builtin_bit_cast(unsigned, f);
  return (unsigned short)((u + 0x7FFFu + ((u >> 16) & 1u)) >> 16);
}
DEV float bf2f(unsigned short h) {
  unsigned u = ((unsigned)h) << 16;
  return __builtin_bit_cast(float, u);
}

// TBAA-safe vector ld/st (memcpy compiles to single b128/b64 with assumed alignment)
DEV short8 ld_s8(const void* p) {
  short8 v; __builtin_memcpy(&v, __builtin_assume_aligned(p, 16), 16); return v;
}
DEV uintx4 ld_u4(const void* p) {
  uintx4 v; __builtin_memcpy(&v, __builtin_assume_aligned(p, 16), 16); return v;
}
DEV void st_u4(void* p, uintx4 v) {
  __builtin_memcpy(__builtin_assume_aligned(p, 16), &v, 16);
}
DEV void st_us4(void* p, ushortx4 v) {
  __builtin_memcpy(__builtin_assume_aligned(p, 8), &v, 8);
}
DEV float4 ld_f4(const void* p) {
  float4 v; __builtin_memcpy(&v, __builtin_assume_aligned(p, 16), 16); return v;
}

DEV void async_lds16(const void* g, const void* l) {  // global -> LDS DMA, 16B/lane
  __builtin_amdgcn_global_load_lds(
      (const __attribute__((address_space(1))) unsigned int*)g,
      (__attribute__((address_space(3))) unsigned int*)l, 16, 0, 0);
}

// ---------------------------------------------------------------------------
// Kernel 1: QKV projection. grid (256, 1, 3), block 256.
// z=0: Q = x Wq^T + bq -> Qb[N][D] bf16
// z=1: K = dx Wk^T + bk -> Kb[M][D] bf16
// z=2: V = dx Wv^T + bv -> VTb[D][M] bf16 (transposed store)
// Tile: 32 rows x 512 cols, BK=32. A/x read exactly once; W (1MB) L2-resident.
// ---------------------------------------------------------------------------
__global__ __launch_bounds__(256, 2)
void qkv_proj(const float* __restrict__ x, const float* __restrict__ dx,
              const float* __restrict__ Wq, const float* __restrict__ bq,
              const float* __restrict__ Wk, const float* __restrict__ bk,
              const float* __restrict__ Wv, const float* __restrict__ bv,
              unsigned short* __restrict__ Qb, unsigned short* __restrict__ Kb,
              unsigned short* __restrict__ VTb) {
  const int z = blockIdx.z;
  const float* A = (z == 0) ? x : dx;
  const float* W = (z == 0) ? Wq : (z == 1) ? Wk : Wv;
  const float* bias = (z == 0) ? bq : (z == 1) ? bk : bv;

  const int r0 = blockIdx.x * 32;
  const int tid = threadIdx.x;
  const int lane = tid & 63;
  const int wave = tid >> 6;
  const int lr = lane & 15;
  const int quad = lane >> 4;

  // row stride 40 ushorts = 80 B (16-mult, bank-uniform)
  __shared__ __align__(16) unsigned short As[32 * 40];
  __shared__ __align__(16) unsigned short Ws[512 * 40];

  floatx4 acc[2][8];
#pragma unroll
  for (int i = 0; i < 2; ++i)
#pragma unroll
    for (int j = 0; j < 8; ++j) acc[i][j] = {0.f, 0.f, 0.f, 0.f};

  for (int k0 = 0; k0 < DD; k0 += 32) {
    {  // stage A tile: 32 rows x 8 float4 = 256 items (1/thread), convert to bf16
      int r = tid >> 3, c4 = tid & 7;
      float4 v = ld_f4(A + (size_t)(r0 + r) * DD + k0 + c4 * 4);
      ushortx4 pk = {f2bf(v.x), f2bf(v.y), f2bf(v.z), f2bf(v.w)};
      st_us4(&As[r * 40 + c4 * 4], pk);
    }
#pragma unroll
    for (int i = 0; i < 16; ++i) {  // stage W tile: 512 rows x 8 items
      int idx = i * 256 + tid;
      int r = idx >> 3, c4 = idx & 7;
      float4 v = ld_f4(W + (size_t)r * DD + k0 + c4 * 4);
      ushortx4 pk = {f2bf(v.x), f2bf(v.y), f2bf(v.z), f2bf(v.w)};
      st_us4(&Ws[r * 40 + c4 * 4], pk);
    }
    __syncthreads();

    short8 a0 = ld_s8(&As[(0 * 16 + lr) * 40 + quad * 8]);
    short8 a1 = ld_s8(&As[(1 * 16 + lr) * 40 + quad * 8]);
#pragma unroll
    for (int ct = 0; ct < 8; ++ct) {
      short8 b = ld_s8(&Ws[(wave * 128 + ct * 16 + lr) * 40 + quad * 8]);
      acc[0][ct] = __builtin_amdgcn_mfma_f32_16x16x32_bf16(a0, b, acc[0][ct], 0, 0, 0);
      acc[1][ct] = __builtin_amdgcn_mfma_f32_16x16x32_bf16(a1, b, acc[1][ct], 0, 0, 0);
    }
    __syncthreads();
  }

  // epilogue: bias + store (C layout: col = lane&15, row = quad*4 + reg)
  unsigned short* Outp = (z == 0) ? Qb : Kb;
#pragma unroll
  for (int ct = 0; ct < 8; ++ct) {
    int col = wave * 128 + ct * 16 + lr;
    float bv_ = bias[col];
#pragma unroll
    for (int rt = 0; rt < 2; ++rt) {
      int rowb = r0 + rt * 16 + quad * 4;
      if (z == 2) {  // transposed: VT[col][row], 4 consecutive rows -> 8B store
        ushortx4 pk = {f2bf(acc[rt][ct][0] + bv_), f2bf(acc[rt][ct][1] + bv_),
                       f2bf(acc[rt][ct][2] + bv_), f2bf(acc[rt][ct][3] + bv_)};
        st_us4(VTb + (size_t)col * MM + rowb, pk);
      } else {
#pragma unroll
        for (int r = 0; r < 4; ++r)
          Outp[(size_t)(rowb + r) * DD + col] = f2bf(acc[rt][ct][r] + bv_);
      }
    }
  }
}

// ---------------------------------------------------------------------------
// Kernel 2: flash attention. grid (N/64, SPLITS), block 256 (4 waves).
// Wave w owns q-rows [n0+16w, n0+16w+16): softmax state is wave-private.
// Per iter (BM=64): K tile via global_load_lds (row-exact DMA), S = Q K^T,
// online softmax, P -> LDS (layout transform), VT tile (xor-swizzled) -> PV.
// LDS 75,776 B. Writes unnormalized O (bf16) + per-row m,l partials.
// ---------------------------------------------------------------------------
__global__ __launch_bounds__(256, 1)
void flash_attn(const unsigned short* __restrict__ Qb,
                const unsigned short* __restrict__ Kb,
                const unsigned short* __restrict__ VTb,
                unsigned short* __restrict__ Opart,
                float* __restrict__ Mpart, float* __restrict__ Lpart) {
  constexpr int MT = MM / SPLITS;
  constexpr int ITERS = MT / 64;
  const int n0 = blockIdx.x * 64;
  const int split = blockIdx.y;
  const int m_begin = split * MT;

  const int tid = threadIdx.x;
  const int lane = tid & 63;
  const int wave = tid >> 6;
  const int lr = lane & 15;
  const int quad = lane >> 4;

  // sKV: K phase rows stride 520 us (1040B, DMA-compatible pad); VT phase rows
  // stride 64 us (128B) with chunk^=(row&7) xor swizzle. Both conflict-uniform.
  __shared__ __align__(16) unsigned short sKV[33280];      // 66,560 B
  __shared__ __align__(16) unsigned short sP[4 * 16 * 72]; // 9,216 B
  unsigned short* myP = &sP[wave * 16 * 72];

  // resident Q fragments: wave's 16 rows x 512 k (64 VGPRs)
  short8 qf[16];
  const unsigned short* qptr = Qb + (size_t)(n0 + wave * 16 + lr) * DD + quad * 8;
#pragma unroll
  for (int ks = 0; ks < 16; ++ks) qf[ks] = ld_s8(qptr + ks * 32);

  floatx4 o[32];
#pragma unroll
  for (int i = 0; i < 32; ++i) o[i] = {0.f, 0.f, 0.f, 0.f};
  float mrow[4] = {NEG_INF, NEG_INF, NEG_INF, NEG_INF};
  float lrow[4] = {0.f, 0.f, 0.f, 0.f};

  for (int it = 0; it < ITERS; ++it) {
    const int m0 = m_begin + it * 64;

    // ---- stage K tile: one DMA per row (64 lanes x 16B = exactly 1024B row)
#pragma unroll
    for (int i = 0; i < 16; ++i) {
      const int r = wave * 16 + i;  // wave-uniform LDS dest
      async_lds16(Kb + (size_t)(m0 + r) * DD + lane * 8, &sKV[r * 520]);
    }
    __syncthreads();  // drains vmcnt -> K visible

    // ---- S = Q K^T (wave: 16 rows x 64 cols)
    floatx4 s[4];
#pragma unroll
    for (int ct = 0; ct < 4; ++ct) s[ct] = {0.f, 0.f, 0.f, 0.f};
#pragma unroll
    for (int ks = 0; ks < 16; ++ks) {
      const unsigned short* kb = &sKV[ks * 32 + quad * 8];
#pragma unroll
      for (int ct = 0; ct < 4; ++ct) {
        short8 b = ld_s8(kb + (ct * 16 + lr) * 520);
        s[ct] = __builtin_amdgcn_mfma_f32_16x16x32_bf16(qf[ks], b, s[ct], 0, 0, 0);
      }
    }
    __syncthreads();  // all waves done with K region

    // ---- prefetch VT tile into regs (latency overlaps softmax VALU)
    uintx4 vt[16];
#pragma unroll
    for (int i = 0; i < 16; ++i) {
      int idx = i * 256 + tid;
      int r = idx >> 3, c = idx & 7;
      vt[i] = ld_u4(VTb + (size_t)r * MM + m0 + c * 8);
    }

    // ---- online softmax (rows quad*4+reg, cols across 16 lanes of the quad)
    float alpha[4];
#pragma unroll
    for (int r = 0; r < 4; ++r) {
      float mx = NEG_INF;
#pragma unroll
      for (int ct = 0; ct < 4; ++ct) {
        s[ct][r] *= SCALE2;  // logits in log2 units
        mx = fmaxf(mx, s[ct][r]);
      }
      mx = fmaxf(mx, __shfl_xor(mx, 1));
      mx = fmaxf(mx, __shfl_xor(mx, 2));
      mx = fmaxf(mx, __shfl_xor(mx, 4));
      mx = fmaxf(mx, __shfl_xor(mx, 8));
      float mnew = fmaxf(mrow[r], mx);
      alpha[r] = EXP2F(mrow[r] - mnew);  // first iter: exp2(-inf) = 0
      mrow[r] = mnew;
      float rs = 0.f;
#pragma unroll
      for (int ct = 0; ct < 4; ++ct) {
        float p = EXP2F(s[ct][r] - mnew);
        s[ct][r] = p;
        rs += p;
      }
      rs += __shfl_xor(rs, 1);
      rs += __shfl_xor(rs, 2);
      rs += __shfl_xor(rs, 4);
      rs += __shfl_xor(rs, 8);
      lrow[r] = lrow[r] * alpha[r] + rs;
    }
    if (__any(alpha[0] < 1.f || alpha[1] < 1.f || alpha[2] < 1.f || alpha[3] < 1.f)) {
#pragma unroll
      for (int ct = 0; ct < 32; ++ct)
#pragma unroll
        for (int r = 0; r < 4; ++r) o[ct][r] *= alpha[r];
    }

    // ---- P (C layout) -> LDS bf16 [16][72] (read back in A layout)
#pragma unroll
    for (int ct = 0; ct < 4; ++ct)
#pragma unroll
      for (int r = 0; r < 4; ++r)
        myP[(quad * 4 + r) * 72 + ct * 16 + lr] = f2bf(s[ct][r]);

    // ---- write VT tile (xor swizzle per row)
#pragma unroll
    for (int i = 0; i < 16; ++i) {
      int idx = i * 256 + tid;
      int r = idx >> 3, c = idx & 7;
      st_u4(&sKV[r * 64 + (c ^ (r & 7)) * 8], vt[i]);
    }
    __syncthreads();  // VT visible

    // ---- O += P V : A = P[16 x 64], B = VT rows (d), 32 col-tiles
    short8 pa0 = ld_s8(myP + lr * 72 + 0 * 32 + quad * 8);
    short8 pa1 = ld_s8(myP + lr * 72 + 1 * 32 + quad * 8);
#pragma unroll
    for (int ct = 0; ct < 32; ++ct) {
      const int row = ct * 16 + lr;
      const unsigned short* vb = &sKV[row * 64];
      const int sw = row & 7;
      short8 b0 = ld_s8(vb + ((0 + quad) ^ sw) * 8);
      o[ct] = __builtin_amdgcn_mfma_f32_16x16x32_bf16(pa0, b0, o[ct], 0, 0, 0);
      short8 b1 = ld_s8(vb + ((4 + quad) ^ sw) * 8);
      o[ct] = __builtin_amdgcn_mfma_f32_16x16x32_bf16(pa1, b1, o[ct], 0, 0, 0);
    }
    __syncthreads();  // region free for next iter's K DMA
  }

  // ---- epilogue: unnormalized partials
  const int grow = n0 + wave * 16 + quad * 4;
  unsigned short* op = Opart + (size_t)split * NN * DD;
#pragma unroll
  for (int ct = 0; ct < 32; ++ct) {
    int col = ct * 16 + lr;
#pragma unroll
    for (int r = 0; r < 4; ++r)
      op[(size_t)(grow + r) * DD + col] = f2bf(o[ct][r]);
  }
  if (lr == 0) {
#pragma unroll
    for (int r = 0; r < 4; ++r) {
      Mpart[split * NN + grow + r] = mrow[r];
      Lpart[split * NN + grow + r] = lrow[r];
    }
  }
}

// ---------------------------------------------------------------------------
// Kernel 3: exact softmax merge of SPLITS partials. grid (N*D/256), block 256.
// ---------------------------------------------------------------------------
__global__ void combine_kernel(const unsigned short* __restrict__ Op,
                               const float* __restrict__ Mp,
                               const float* __restrict__ Lp,
                               float* __restrict__ out) {
  constexpr size_t NDv = (size_t)NN * DD;
  size_t idx = (size_t)blockIdx.x * 256 + threadIdx.x;
  int n = (int)(idx >> 9);
  float mv[SPLITS];
  float ms = NEG_INF;
#pragma unroll
  for (int s = 0; s < SPLITS; ++s) {
    mv[s] = Mp[s * NN + n];
    ms = fmaxf(ms, mv[s]);
  }
  float num = 0.f, den = 0.f;
#pragma unroll
  for (int s = 0; s < SPLITS; ++s) {
    float w = EXP2F(mv[s] - ms);
    den += w * Lp[s * NN + n];
    num += w * bf2f(Op[s * NDv + idx]);
  }
  out[idx] = num / den;
}

// ---------------------------------------------------------------------------
extern "C" void kernel_launch(void* const* d_in, const int* in_sizes, int n_in,
                              void* d_out, int out_size, void* d_ws, size_t ws_size,
                              hipStream_t stream) {
  const float* x  = (const float*)d_in[0];
  const float* dx = (const float*)d_in[1];
  const float* Wq = (const float*)d_in[2];
  const float* bq = (const float*)d_in[3];
  const float* Wk = (const float*)d_in[4];
  const float* bk = (const float*)d_in[5];
  const float* Wv = (const float*)d_in[6];
  const float* bv = (const float*)d_in[7];
  float* out = (float*)d_out;

  const size_t ND = (size_t)NN * DD;  // 4,194,304
  unsigned short* Qb  = (unsigned short*)d_ws;  // bf16, ND
  unsigned short* Kb  = Qb + ND;                // bf16, ND
  unsigned short* VTb = Kb + ND;                // bf16, ND (transposed V)
  unsigned short* Op  = VTb + ND;               // bf16, SPLITS*ND partial O
  float* Mp = (float*)(Op + (size_t)SPLITS * ND);  // SPLITS*N
  float* Lp = Mp + (size_t)SPLITS * NN;            // SPLITS*N
  // total ws: ~40.3 MB

  hipLaunchKernelGGL(qkv_proj, dim3(NN / 32, 1, 3), dim3(256), 0, stream,
                     x, dx, Wq, bq, Wk, bk, Wv, bv, Qb, Kb, VTb);
  hipLaunchKernelGGL(flash_attn, dim3(NN / 64, SPLITS), dim3(256), 0, stream,
                     Qb, Kb, VTb, Op, Mp, Lp);
  hipLaunchKernelGGL(combine_kernel, dim3((unsigned)(ND / 256)), dim3(256), 0, stream,
                     Op, Mp, Lp, out);
}